// Round 5
// baseline (1167.801 us; speedup 1.0000x reference)
//
#include <hip/hip_runtime.h>
#include <hip/hip_bf16.h>
#include <math.h>

using bf16 = __hip_bfloat16;

#define H_IMG 128
#define W_IMG 128
#define C_IN  200
#define NCLS  16
#define N0    16384
#define N1    4096
#define N2    1024
#define KNB   16
#define EPS   1e-5f
#define SLOPE 0.01f

__device__ __forceinline__ float leaky(float v) { return v >= 0.f ? v : SLOPE * v; }
__device__ __forceinline__ float ldw(const void* p, long i, int fl) {
    return fl ? ((const float*)p)[i] : __bfloat162float(((const bf16*)p)[i]);
}
__device__ __forceinline__ float4 ld4(const float* p, long i) {
    return *reinterpret_cast<const float4*>(p + i);
}
__device__ __forceinline__ float4 ld4(const bf16* p, long i) {
    const ushort4 u = *reinterpret_cast<const ushort4*>(reinterpret_cast<const unsigned short*>(p) + i);
    float4 r;
    r.x = __uint_as_float((unsigned)u.x << 16);
    r.y = __uint_as_float((unsigned)u.y << 16);
    r.z = __uint_as_float((unsigned)u.z << 16);
    r.w = __uint_as_float((unsigned)u.w << 16);
    return r;
}
__device__ __forceinline__ float4 ld4w(const void* p, long i, int fl) {
    return fl ? ld4((const float*)p, i) : ld4((const bf16*)p, i);
}

// ---------- per-block dtype detect ----------
__device__ __forceinline__ int block_detect(const unsigned short* __restrict__ x) {
    __shared__ int cnt_s;
    if (threadIdx.x == 0) cnt_s = 0;
    __syncthreads();
    int cnt = 0;
    for (int i = threadIdx.x; i < 4096; i += blockDim.x) {
        unsigned short e = (unsigned short)((x[i] >> 7) & 0xFF);
        if (e >= 0xC0) cnt++;
    }
#pragma unroll
    for (int off = 32; off > 0; off >>= 1) cnt += __shfl_xor(cnt, off, 64);
    if ((threadIdx.x & 63) == 0) atomicAdd(&cnt_s, cnt);
    __syncthreads();
    return cnt_s > 32 ? 1 : 0;
}

// ---------------- K0: prep — detect + transpose o-major 1x1 weights to c-major f32 ----------------
__global__ __launch_bounds__(256) void prep_kernel(const void* __restrict__ x,
                                                   const void* __restrict__ hpw, const void* __restrict__ tpw,
                                                   float* __restrict__ WHc, float* __restrict__ WTc,
                                                   int* __restrict__ dflag) {
    int fl = block_detect((const unsigned short*)x);
    if (blockIdx.x == 0 && threadIdx.x == 0) *dflag = fl;
    if (blockIdx.x < 8) {
        for (long e = blockIdx.x * 256 + threadIdx.x; e < 128L * C_IN; e += 8 * 256) {
            int j = (int)(e / C_IN), c = (int)(e - (long)j * C_IN);
            WHc[(long)c * 128 + j] = ldw(hpw, e, fl);
        }
    } else {
        for (long e = (blockIdx.x - 8) * 256 + threadIdx.x; e < 128L * 192; e += 8 * 256) {
            int j = (int)(e / 192), c = (int)(e - (long)j * 192);
            WTc[(long)c * 128 + j] = ldw(tpw, e, fl);
        }
    }
}

// ---------------- K1: head BN stage A ----------------
__global__ __launch_bounds__(256) void bnx_kernel(const void* __restrict__ X, float2* __restrict__ part) {
    int fl = block_detect((const unsigned short*)X);
    int b = blockIdx.x, t = threadIdx.x;
    if (t >= C_IN) return;
    float s = 0.f, s2 = 0.f;
    if (fl) {
        const float* p = (const float*)X + (long)b * 64 * C_IN + t;
        for (int r = 0; r < 64; r++) { float v = p[(long)r * C_IN]; s += v; s2 += v * v; }
    } else {
        const bf16* p = (const bf16*)X + (long)b * 64 * C_IN + t;
        for (int r = 0; r < 64; r++) { float v = __bfloat162float(p[(long)r * C_IN]); s += v; s2 += v * v; }
    }
    part[(long)t * 256 + b] = make_float2(s, s2);
}

// ---------------- fused fold+GEMM body ----------------
// smem layout: al[0..255], be[256..511], bs[512..639], wls[640..]
// WRAW=1: Wsrc is raw input weights (dtype by fl), c-major [CI][CO].
// WRAW=0: Wsrc is pre-transposed f32 c-major.
// CAT=1: input c<SPLIT from A2[row>>2][c] (stride sA2), else In[row][c-SPLIT] (stride sIn).
template <typename TIN, int CI, int CO, int KT, int ACT, int CAT, int SPLIT, int WRAW>
__device__ __forceinline__ void gemmF_body(const TIN* __restrict__ In, int sIn,
                                           const float* __restrict__ A2, int sA2,
                                           const void* __restrict__ Wsrc, const void* __restrict__ bvec,
                                           const float2* __restrict__ pA, int npA, int splitC,
                                           const float2* __restrict__ pB, int npB, float Pinv,
                                           const void* __restrict__ g, const void* __restrict__ bt,
                                           int fl, float* __restrict__ Out, int blk, float* smem) {
    float* al = smem;
    float* be = smem + 256;
    float* bs = smem + 512;
    float* wls = smem + 640;
    int t = threadIdx.x;
    // alpha/beta from partials
    if (t < CI) {
        const float2* src = (t < splitC) ? pA + (long)t * npA : pB + (long)(t - splitC) * npB;
        int np = (t < splitC) ? npA : npB;
        float s = 0.f, s2 = 0.f;
        const float4* p4 = (const float4*)src;
        for (int i = 0; i < (np >> 1); i++) { float4 v = p4[i]; s += v.x + v.z; s2 += v.y + v.w; }
        float mu = s * Pinv;
        float var = s2 * Pinv - mu * mu;
        float aa = rsqrtf(var + EPS) * ldw(g, t, fl);
        al[t] = aa;
        be[t] = ldw(bt, t, fl) - mu * aa;
    }
    __syncthreads();
    // bias fold: bs[j] = bias[j] + sum_c Wraw[c][j]*be[c]
    if (t < CO) {
        float s = ldw(bvec, t, fl);
        for (int c = 0; c < CI; c++) {
            float w = WRAW ? ldw(Wsrc, (long)c * CO + t, fl) : ((const float*)Wsrc)[(long)c * CO + t];
            s += w * be[c];
        }
        bs[t] = s;
    }
    __syncthreads();
    constexpr int NQ = CO / 4;
    constexpr int SH = (NQ == 32) ? 5 : (NQ == 16) ? 4 : 3;
    constexpr int L2CO = (CO == 128) ? 7 : (CO == 64) ? 6 : 5;
    constexpr int RPB = 512 / NQ;
    int jq = t & (NQ - 1), rp = t >> SH;
    int r0 = blk * RPB + rp * 2, r1 = r0 + 1;
    float4 a0 = *reinterpret_cast<float4*>(&bs[jq * 4]);
    float4 a1 = a0;
    for (int kt = 0; kt < CI; kt += KT) {
        // stage folded weight tile
        for (int e4 = t * 4; e4 < KT * CO; e4 += 1024) {
            int cc = e4 >> L2CO, j4 = e4 & (CO - 1);
            float aa = al[kt + cc];
            float4 w = WRAW ? ld4w(Wsrc, (long)(kt + cc) * CO + j4, fl)
                            : ld4((const float*)Wsrc, (long)(kt + cc) * CO + j4);
            *reinterpret_cast<float4*>(&wls[e4]) = make_float4(w.x * aa, w.y * aa, w.z * aa, w.w * aa);
        }
        __syncthreads();
        for (int cc = 0; cc < KT; cc += 4) {
            int c = kt + cc;
            float4 x0, x1;
            if (CAT) {
                if (c < SPLIT) {
                    x0 = ld4(A2 + (long)(r0 >> 2) * sA2, c);
                    x1 = ld4(A2 + (long)(r1 >> 2) * sA2, c);
                } else {
                    x0 = ld4((const float*)(const void*)In + (long)r0 * sIn, c - SPLIT);
                    x1 = ld4((const float*)(const void*)In + (long)r1 * sIn, c - SPLIT);
                }
            } else {
                x0 = ld4(In + (long)r0 * sIn, c);
                x1 = ld4(In + (long)r1 * sIn, c);
            }
            const float* wp = &wls[cc * CO + jq * 4];
            float4 w0 = *(const float4*)wp;
            float4 w1 = *(const float4*)(wp + CO);
            float4 w2 = *(const float4*)(wp + 2 * CO);
            float4 w3 = *(const float4*)(wp + 3 * CO);
            a0.x += x0.x * w0.x; a0.y += x0.x * w0.y; a0.z += x0.x * w0.z; a0.w += x0.x * w0.w;
            a1.x += x1.x * w0.x; a1.y += x1.x * w0.y; a1.z += x1.x * w0.z; a1.w += x1.x * w0.w;
            a0.x += x0.y * w1.x; a0.y += x0.y * w1.y; a0.z += x0.y * w1.z; a0.w += x0.y * w1.w;
            a1.x += x1.y * w1.x; a1.y += x1.y * w1.y; a1.z += x1.y * w1.z; a1.w += x1.y * w1.w;
            a0.x += x0.z * w2.x; a0.y += x0.z * w2.y; a0.z += x0.z * w2.z; a0.w += x0.z * w2.w;
            a1.x += x1.z * w2.x; a1.y += x1.z * w2.y; a1.z += x1.z * w2.z; a1.w += x1.z * w2.w;
            a0.x += x0.w * w3.x; a0.y += x0.w * w3.y; a0.z += x0.w * w3.z; a0.w += x0.w * w3.w;
            a1.x += x1.w * w3.x; a1.y += x1.w * w3.y; a1.z += x1.w * w3.z; a1.w += x1.w * w3.w;
        }
        __syncthreads();
    }
    if (ACT) {
        a0.x = leaky(a0.x); a0.y = leaky(a0.y); a0.z = leaky(a0.z); a0.w = leaky(a0.w);
        a1.x = leaky(a1.x); a1.y = leaky(a1.y); a1.z = leaky(a1.z); a1.w = leaky(a1.w);
    }
    *reinterpret_cast<float4*>(Out + (long)r0 * CO + jq * 4) = a0;
    *reinterpret_cast<float4*>(Out + (long)r1 * CO + jq * 4) = a1;
}

// ---- K2: head GEMM (fold fused) ----
__global__ __launch_bounds__(256) void gemmF_head_kernel(const void* x, const float* WHc, const void* hpb,
                                                         const float2* pH, const void* hg, const void* hb_,
                                                         float* R0, const int* dflag) {
    extern __shared__ float smem[];
    int fl = *dflag;
    if (fl) gemmF_body<float, C_IN, 128, 40, 1, 0, 0, 0>((const float*)x, C_IN, nullptr, 0, WHc, hpb,
                                                         pH, 256, C_IN, pH, 256, 1.f / (float)N0,
                                                         hg, hb_, 1, R0, (int)blockIdx.x, smem);
    else    gemmF_body<bf16, C_IN, 128, 40, 1, 0, 0, 0>((const bf16*)x, C_IN, nullptr, 0, WHc, hpb,
                                                        pH, 256, C_IN, pH, 256, 1.f / (float)N0,
                                                        hg, hb_, 0, R0, (int)blockIdx.x, smem);
}

// ---- K4: e0 GEMMs (fold fused) ----
__global__ __launch_bounds__(256) void gemmF_e0_kernel(const float* H1b,
                                                       const void* wt, const void* bt_, const void* wo, const void* bo,
                                                       const float2* pE0, const void* g, const void* b_,
                                                       float* TH, float* OU, const int* dflag) {
    extern __shared__ float smem[];
    int fl = *dflag;
    if (blockIdx.x < 256)
        gemmF_body<float, 128, 128, 64, 0, 0, 0, 1>(H1b, 128, nullptr, 0, wt, bt_,
                                                    pE0, 512, 128, pE0, 512, 1.f / (float)N1,
                                                    g, b_, fl, TH, (int)blockIdx.x, smem);
    else
        gemmF_body<float, 128, 64, 128, 0, 0, 0, 1>(H1b, 128, nullptr, 0, wo, bo,
                                                    pE0, 512, 128, pE0, 512, 1.f / (float)N1,
                                                    g, b_, fl, OU, (int)blockIdx.x - 256, smem);
}

// ---- K6: e1 GEMMs ----
__global__ __launch_bounds__(256) void gemmF_e1_kernel(const float* H2b,
                                                       const void* wt, const void* bt_, const void* wo, const void* bo,
                                                       const float2* pE1, const void* g, const void* b_,
                                                       float* TH, float* OU, const int* dflag) {
    extern __shared__ float smem[];
    int fl = *dflag;
    if (blockIdx.x < 64)
        gemmF_body<float, 64, 128, 64, 0, 0, 0, 1>(H2b, 64, nullptr, 0, wt, bt_,
                                                   pE1, 1024, 64, pE1, 1024, 1.f / (float)N2,
                                                   g, b_, fl, TH, (int)blockIdx.x, smem);
    else
        gemmF_body<float, 64, 32, 64, 0, 0, 0, 1>(H2b, 64, nullptr, 0, wo, bo,
                                                  pE1, 1024, 64, pE1, 1024, 1.f / (float)N2,
                                                  g, b_, fl, OU, (int)blockIdx.x - 64, smem);
}

// ---- K8: d0 GEMMs (virtual concat [HDb | ENC1]) ----
__global__ __launch_bounds__(256) void gemmF_d0_kernel(const float* ENC1, const float* HDb,
                                                       const void* wt, const void* bt_, const void* wo, const void* bo,
                                                       const float2* pD0a, const float2* pD0b,
                                                       const void* g, const void* b_,
                                                       float* TH, float* OU, const int* dflag) {
    extern __shared__ float smem[];
    int fl = *dflag;
    if (blockIdx.x < 256)
        gemmF_body<float, 96, 128, 48, 0, 1, 32, 1>(ENC1, 64, HDb, 32, wt, bt_,
                                                    pD0a, 256, 32, pD0b, 1024, 1.f / (float)N1,
                                                    g, b_, fl, TH, (int)blockIdx.x, smem);
    else
        gemmF_body<float, 96, 64, 96, 0, 1, 32, 1>(ENC1, 64, HDb, 32, wo, bo,
                                                   pD0a, 256, 32, pD0b, 1024, 1.f / (float)N1,
                                                   g, b_, fl, OU, (int)blockIdx.x - 256, smem);
}

// ---- K10: tail GEMM (virtual concat [HDEC | enc0]) ----
__global__ __launch_bounds__(256) void gemmF_tail_kernel(const float* R1, const float* HDEC,
                                                         const float* WTc, const void* tpb,
                                                         const float2* pTa, const float2* pTb,
                                                         const void* g, const void* b_,
                                                         float* T1, const int* dflag) {
    extern __shared__ float smem[];
    int fl = *dflag;
    gemmF_body<float, 192, 128, 48, 1, 1, 64, 0>(R1, 128, HDEC, 64, WTc, tpb,
                                                 pTa, 1024, 64, pTb, 512, 1.f / (float)N0,
                                                 g, b_, fl, T1, (int)blockIdx.x, smem);
}

// ---------------- depthwise 5x5 helpers ----------------
__device__ __forceinline__ void dw_load(const void* dwp, const void* dbp, float* wl, float* bl, int fl) {
    int t = threadIdx.x;
    for (int e = t; e < 25 * 128; e += 256) {
        int o = e / 25, i = e - o * 25;
        wl[i * 128 + o] = ldw(dwp, e, fl);
    }
    if (t < 128) bl[t] = ldw(dbp, t, fl);
}

__device__ __forceinline__ float4 dw_compute(int p, int o0, const float* __restrict__ In,
                                             const float* wl, const float* bl) {
    int h = p >> 7, w = p & 127;
    float4 acc = *reinterpret_cast<const float4*>(&bl[o0]);
#pragma unroll
    for (int dh = -2; dh <= 2; dh++) {
        int hh = h + dh;
        if ((unsigned)hh >= (unsigned)H_IMG) continue;
#pragma unroll
        for (int dv = -2; dv <= 2; dv++) {
            int ww = w + dv;
            if ((unsigned)ww >= (unsigned)W_IMG) continue;
            float4 iv = *reinterpret_cast<const float4*>(&In[(long)(((hh << 7) + ww) << 7) + o0]);
            float4 wv = *reinterpret_cast<const float4*>(&wl[((dh + 2) * 5 + (dv + 2)) * 128 + o0]);
            acc.x += iv.x * wv.x; acc.y += iv.y * wv.y; acc.z += iv.z * wv.z; acc.w += iv.w * wv.w;
        }
    }
    acc.x = leaky(acc.x); acc.y = leaky(acc.y); acc.z = leaky(acc.z); acc.w = leaky(acc.w);
    return acc;
}

// ---------------- K3: head dw + pool4 + e0 stats + tail raw stats (grid 512) ----------------
__global__ __launch_bounds__(256) void dwpool_kernel(const float* __restrict__ In, const void* dwp, const void* dbp,
                                                     float* __restrict__ R1out, float* __restrict__ H1b,
                                                     float2* __restrict__ pE0, float2* __restrict__ pTb,
                                                     const int* dflag) {
    __shared__ float wl[25 * 128];
    __shared__ float bl[128];
    __shared__ float sm[8 * 132];
    int fl = *dflag;
    dw_load(dwp, dbp, wl, bl, fl);
    __syncthreads();
    int t = threadIdx.x;
    int o0 = (t & 31) << 2, pxl = t >> 5;
    float s = 0.f, s2 = 0.f, rs = 0.f, rs2 = 0.f;
    for (int it = 0; it < 4; it++) {
        int p = blockIdx.x * 32 + it * 8 + pxl;
        float4 acc = dw_compute(p, o0, In, wl, bl);
        *reinterpret_cast<float4*>(&R1out[(long)p * 128 + o0]) = acc;
        *reinterpret_cast<float4*>(&sm[pxl * 132 + o0]) = acc;
        __syncthreads();
        if (t < 128) {
#pragma unroll
            for (int g = 0; g < 2; g++) {
                float v0 = sm[(g * 4 + 0) * 132 + t], v1 = sm[(g * 4 + 1) * 132 + t];
                float v2 = sm[(g * 4 + 2) * 132 + t], v3 = sm[(g * 4 + 3) * 132 + t];
                float h = 0.25f * (v0 + v1 + v2 + v3);
                H1b[(long)(blockIdx.x * 8 + it * 2 + g) * 128 + t] = h;
                s += h; s2 += h * h;
                rs += v0 + v1 + v2 + v3;
                rs2 += v0 * v0 + v1 * v1 + v2 * v2 + v3 * v3;
            }
        }
        __syncthreads();
    }
    if (t < 128) {
        pE0[(long)t * 512 + blockIdx.x] = make_float2(s, s2);
        pTb[(long)t * 512 + blockIdx.x] = make_float2(rs, rs2);
    }
}

// ---------------- K11: tail dw + classifier + softmax (grid 2048) ----------------
__global__ __launch_bounds__(256) void dwcls_kernel(const float* __restrict__ In, const void* dwp, const void* dbp,
                                                    const void* wsw, const void* wb, void* __restrict__ out,
                                                    const int* dflag) {
    __shared__ float wl[25 * 128];
    __shared__ float bl[128];
    __shared__ float cw[2048];
    __shared__ float F[8 * 132];
    int fl = *dflag;
    dw_load(dwp, dbp, wl, bl, fl);
    int t = threadIdx.x;
    for (int e = t; e < 2048; e += 256) cw[e] = ldw(wsw, e, fl);
    __syncthreads();
    int o0 = (t & 31) << 2, pxl = t >> 5;
    int p = blockIdx.x * 8 + pxl;
    float4 acc = dw_compute(p, o0, In, wl, bl);
    *reinterpret_cast<float4*>(&F[pxl * 132 + o0]) = acc;
    __syncthreads();
    if (t < 128) {
        int px = t >> 4, j = t & 15;
        float a = ldw(wb, j, fl);
        const float* fp = &F[px * 132];
#pragma unroll 8
        for (int c = 0; c < 128; c += 4) {
            float4 fv = *reinterpret_cast<const float4*>(fp + c);
            a += fv.x * cw[c * 16 + j] + fv.y * cw[(c + 1) * 16 + j]
               + fv.z * cw[(c + 2) * 16 + j] + fv.w * cw[(c + 3) * 16 + j];
        }
        float m = a;
#pragma unroll
        for (int s = 8; s > 0; s >>= 1) m = fmaxf(m, __shfl_xor(m, s, 16));
        float e = expf(a - m);
        float d = e;
#pragma unroll
        for (int s = 8; s > 0; s >>= 1) d += __shfl_xor(d, s, 16);
        float r = e / d;
        long oi = (long)(blockIdx.x * 8 + px) * 16 + j;
        if (fl) ((float*)out)[oi] = r;
        else ((bf16*)out)[oi] = __float2bfloat16(r);
    }
}

// ---------------- attention (4 rows/block) + fused pool/stat emission ----------------
template <int MODE>
__global__ __launch_bounds__(256) void attn_fused_kernel(const float* __restrict__ th, const float* __restrict__ outm,
                                                         const int* __restrict__ nbr, float* __restrict__ dst, int co,
                                                         float* __restrict__ H2b,
                                                         float2* __restrict__ partP, float2* __restrict__ partS,
                                                         int snp) {
    int wid = threadIdx.x >> 6, l = threadIdx.x & 63;
    int n = blockIdx.x * 4 + wid;
    float r0 = th[(long)n * 128 + l];
    float r1 = th[(long)n * 128 + 64 + l];
    int mk[KNB];
    float av[KNB];
#pragma unroll
    for (int k = 0; k < KNB; k++) {
        int m = nbr[n * KNB + k];
        mk[k] = m;
        float v = r0 * th[(long)m * 128 + l] + r1 * th[(long)m * 128 + 64 + l];
#pragma unroll
        for (int off = 32; off > 0; off >>= 1) v += __shfl_xor(v, off, 64);
        av[k] = 1.f / (1.f + expf(-v));
    }
    float amax = av[0];
#pragma unroll
    for (int k = 1; k < KNB; k++) amax = fmaxf(amax, av[k]);
    float den = 0.f;
#pragma unroll
    for (int k = 0; k < KNB; k++) { av[k] = expf(av[k] - amax); den += av[k]; }
    float rden = 1.f / den;
    float val = 0.f;
    if (l < co) {
        float acc = 0.f;
#pragma unroll
        for (int k = 0; k < KNB; k++) acc += av[k] * outm[(long)mk[k] * co + l];
        val = leaky(acc * rden);
        dst[(long)n * co + l] = val;
    }
    __shared__ float sm[4][64];
    sm[wid][l] = (l < co) ? val : 0.f;
    __syncthreads();
    if (wid == 0 && l < co) {
        float a = sm[0][l], bb = sm[1][l], c = sm[2][l], d = sm[3][l];
        float su = a + bb + c + d;
        float sq = a * a + bb * bb + c * c + d * d;
        if (MODE == 0) {
            float h = 0.25f * su;
            H2b[(long)blockIdx.x * 64 + l] = h;
            partP[(long)l * snp + blockIdx.x] = make_float2(h, h * h);
            partS[(long)l * snp + blockIdx.x] = make_float2(su, sq);
        } else {
            partS[(long)l * snp + blockIdx.x] = make_float2(4.f * su, 4.f * sq);
        }
    }
}

// ================= host side =================
extern "C" void kernel_launch(void* const* d_in, const int* in_sizes, int n_in,
                              void* d_out, int out_size, void* d_ws, size_t ws_size,
                              hipStream_t stream) {
    bool dict = (in_sizes[1] > 1000000);
    int I_x, I_nbr_a, I_nbr_b, I_hg, I_ws, I_e0, I_e1, I_d0, I_tg;
    if (dict) {
        I_x = 0; I_nbr_a = 5; I_nbr_b = 6; I_hg = 7; I_e0 = 13; I_e1 = 19; I_d0 = 25; I_tg = 31; I_ws = 37;
    } else {
        I_x = 0; I_hg = 1; I_e0 = 7; I_e1 = 13; I_d0 = 19; I_tg = 25; I_ws = 31; I_nbr_a = 37; I_nbr_b = 38;
    }
    const void* x    = d_in[I_x];
    const int* nbr_a = (const int*)d_in[I_nbr_a];
    const int* nbr_b = (const int*)d_in[I_nbr_b];
    const void* hg   = d_in[I_hg + 0];
    const void* hb   = d_in[I_hg + 1];
    const void* hpw  = d_in[I_hg + 2];
    const void* hpb  = d_in[I_hg + 3];
    const void* hdw  = d_in[I_hg + 4];
    const void* hdb  = d_in[I_hg + 5];
    const void* e0_g = d_in[I_e0 + 0];
    const void* e0_b = d_in[I_e0 + 1];
    const void* e0_wt= d_in[I_e0 + 2];
    const void* e0_bt= d_in[I_e0 + 3];
    const void* e0_wo= d_in[I_e0 + 4];
    const void* e0_bo= d_in[I_e0 + 5];
    const void* e1_g = d_in[I_e1 + 0];
    const void* e1_b = d_in[I_e1 + 1];
    const void* e1_wt= d_in[I_e1 + 2];
    const void* e1_bt= d_in[I_e1 + 3];
    const void* e1_wo= d_in[I_e1 + 4];
    const void* e1_bo= d_in[I_e1 + 5];
    const void* d0_g = d_in[I_d0 + 0];
    const void* d0_b = d_in[I_d0 + 1];
    const void* d0_wt= d_in[I_d0 + 2];
    const void* d0_bt= d_in[I_d0 + 3];
    const void* d0_wo= d_in[I_d0 + 4];
    const void* d0_bo= d_in[I_d0 + 5];
    const void* tg   = d_in[I_tg + 0];
    const void* tb   = d_in[I_tg + 1];
    const void* tpw  = d_in[I_tg + 2];
    const void* tpb  = d_in[I_tg + 3];
    const void* tdw  = d_in[I_tg + 4];
    const void* tdb  = d_in[I_tg + 5];
    const void* wsw  = d_in[I_ws + 0];
    const void* wb   = d_in[I_ws + 1];

    float* W = (float*)d_ws;
    float*  WHc    = W + 0;                   // 200*128
    float*  WTc    = W + 25600;               // 192*128 -> ends 50176
    int*    dflag  = (int*)(W + 50176);
    float2* P_HEAD = (float2*)(W + 50240);    // 200 x 256 f2 -> +102400 = 152640
    float2* P_E0   = (float2*)(W + 152640);   // 128 x 512 f2 -> +131072 = 283712
    float2* P_Tb   = (float2*)(W + 283712);   // 128 x 512 f2 -> 414784
    float2* P_E1   = (float2*)(W + 414784);   // 64 x 1024 f2 -> 545856
    float2* P_D0a  = (float2*)(W + 545856);   // 32 x 256 f2 -> 562240
    float2* P_D0b  = (float2*)(W + 562240);   // 64 x 1024 f2 -> 693312
    float2* P_Ta   = (float2*)(W + 693312);   // 64 x 1024 f2 -> 824384
    float*  R0     = W + 824384;              // 16384*128
    float*  R1     = R0 + (long)N0 * 128;     // 16384*128 (enc0)
    float*  T1     = R1 + (long)N0 * 128;     // 16384*128
    float*  H1b    = T1 + (long)N0 * 128;     // 4096*128
    float*  THb    = H1b + (long)N1 * 128;    // 4096*128
    float*  OUTb   = THb + (long)N1 * 128;    // 4096*64
    float*  ENC1   = OUTb + (long)N1 * 64;    // 4096*64
    float*  H2b    = ENC1 + (long)N1 * 64;    // 1024*64
    float*  HDb    = H2b + (long)N2 * 64;     // 1024*32
    float*  HDEC   = HDb + (long)N2 * 32;     // 4096*64

    const int SM_HEAD = (640 + 40 * 128) * 4;
    const int SM_E0   = (640 + 8192) * 4;
    const int SM_E1   = (640 + 8192) * 4;
    const int SM_D0   = (640 + 6144) * 4;
    const int SM_TAIL = (640 + 6144) * 4;

    // K0. prep: detect + transpose o-major 1x1 weights
    prep_kernel<<<16, 256, 0, stream>>>(x, hpw, tpw, WHc, WTc, dflag);
    // K1. head BN stage A
    bnx_kernel<<<256, 256, 0, stream>>>(x, P_HEAD);
    // K2. head GEMM (BN-reduce + fold fused) -> R0
    gemmF_head_kernel<<<1024, 256, SM_HEAD, stream>>>(x, WHc, hpb, P_HEAD, hg, hb, R0, dflag);
    // K3. head dw + pool4 + e0/tail stats
    dwpool_kernel<<<512, 256, 0, stream>>>(R0, hdw, hdb, R1, H1b, P_E0, P_Tb, dflag);
    // K4. e0 GEMMs (fold fused)
    gemmF_e0_kernel<<<384, 256, SM_E0, stream>>>(H1b, e0_wt, e0_bt, e0_wo, e0_bo,
                                                 P_E0, e0_g, e0_b, THb, OUTb, dflag);
    // K5. e0 attention -> ENC1 (+H2b, e1 stats, d0 stats ch32..95)
    attn_fused_kernel<0><<<1024, 256, 0, stream>>>(THb, OUTb, nbr_a, ENC1, 64, H2b, P_E1, P_D0b, 1024);
    // K6. e1 GEMMs (fold fused)
    gemmF_e1_kernel<<<80, 256, SM_E1, stream>>>(H2b, e1_wt, e1_bt, e1_wo, e1_bo,
                                                P_E1, e1_g, e1_b, THb, OUTb, dflag);
    // K7. e1 attention -> HDb (+d0 stats ch0..31, x4)
    attn_fused_kernel<1><<<256, 256, 0, stream>>>(THb, OUTb, nbr_b, HDb, 32, nullptr, nullptr, P_D0a, 256);
    // K8. d0 GEMMs (fold fused, virtual concat)
    gemmF_d0_kernel<<<384, 256, SM_D0, stream>>>(ENC1, HDb, d0_wt, d0_bt, d0_wo, d0_bo,
                                                 P_D0a, P_D0b, d0_g, d0_b, THb, OUTb, dflag);
    // K9. d0 attention -> HDEC (+tail stats ch0..63, x4)
    attn_fused_kernel<2><<<1024, 256, 0, stream>>>(THb, OUTb, nbr_a, HDEC, 64, nullptr, nullptr, P_Ta, 1024);
    // K10. tail GEMM (fold fused, virtual concat) -> T1
    gemmF_tail_kernel<<<1024, 256, SM_TAIL, stream>>>(R1, HDEC, WTc, tpb, P_Ta, P_Tb, tg, tb, T1, dflag);
    // K11. tail dw + classifier + softmax
    dwcls_kernel<<<2048, 256, 0, stream>>>(T1, tdw, tdb, wsw, wb, d_out, dflag);
}